// Round 1
// baseline (5948.568 us; speedup 1.0000x reference)
//
#include <hip/hip_runtime.h>
#include <math.h>

#define BB 8
#define TT 1024
#define DD 512
#define NT 64       // tape rows
#define NSL 8       // slices (blocks per batch)
#define DSL 64      // slice width in d
#define PITCH 68    // LDS pitch for tape rows (breaks 64-stride bank aliasing)

// ---------------- cross-block atomics (relaxed, agent scope = cache-bypassing) ----
static __device__ __forceinline__ float aload(const float* p) {
    return __hip_atomic_load(p, __ATOMIC_RELAXED, __HIP_MEMORY_SCOPE_AGENT);
}
static __device__ __forceinline__ void astore(float* p, float v) {
    __hip_atomic_store(p, v, __ATOMIC_RELAXED, __HIP_MEMORY_SCOPE_AGENT);
}

static __device__ __forceinline__ float redux8(float v) {
    v += __shfl_xor(v, 1);
    v += __shfl_xor(v, 2);
    v += __shfl_xor(v, 4);
    return v;
}

// softmax across 64 lanes (call from a full wave; lane i holds score i)
static __device__ __forceinline__ float softmax64(float sc) {
    float m = sc;
    #pragma unroll
    for (int off = 32; off > 0; off >>= 1) m = fmaxf(m, __shfl_xor(m, off));
    float e = __expf(sc - m);
    float s = e;
    #pragma unroll
    for (int off = 32; off > 0; off >>= 1) s += __shfl_xor(s, off);
    return e / s;
}

// dot of 64 weights (16 float4 regs) with 64 LDS floats at hr[0..63]
static __device__ __forceinline__ float dot64(const float4 (&w)[16], const float* hr) {
    float a0 = 0.f, a1 = 0.f, a2 = 0.f, a3 = 0.f;
    #pragma unroll
    for (int j = 0; j < 16; j += 4) {
        float4 h0 = *(const float4*)(hr + 4 * (j + 0));
        float4 h1 = *(const float4*)(hr + 4 * (j + 1));
        float4 h2 = *(const float4*)(hr + 4 * (j + 2));
        float4 h3 = *(const float4*)(hr + 4 * (j + 3));
        a0 += w[j + 0].x * h0.x + w[j + 0].y * h0.y + w[j + 0].z * h0.z + w[j + 0].w * h0.w;
        a1 += w[j + 1].x * h1.x + w[j + 1].y * h1.y + w[j + 1].z * h1.z + w[j + 1].w * h1.w;
        a2 += w[j + 2].x * h2.x + w[j + 2].y * h2.y + w[j + 2].z * h2.z + w[j + 2].w * h2.w;
        a3 += w[j + 3].x * h3.x + w[j + 3].y * h3.y + w[j + 3].z * h3.z + w[j + 3].w * h3.w;
    }
    return (a0 + a1) + (a2 + a3);
}

// ---------------- projection GEMM: xz[m,e] = sum_k x[m,k] * Wxz[e,k] ----------------
// M = 8192, N(e) = 1024, K = 512. e<512 -> xp (stored into d_out region), else -> Zbuf.
__global__ __launch_bounds__(256) void proj_kernel(const float* __restrict__ x,
                                                   const float* __restrict__ Wxz,
                                                   float* __restrict__ xp,
                                                   float* __restrict__ z) {
    __shared__ float As[16][66];
    __shared__ float Bs[16][66];
    const int m0 = blockIdx.x * 64;
    const int n0 = blockIdx.y * 64;
    const int tid = threadIdx.x;
    const int tm = tid / 16, tn = tid % 16;
    float c[4][4] = {};
    for (int k0 = 0; k0 < 512; k0 += 16) {
        const int r = tid >> 2, c4 = (tid & 3) * 4;
        float4 a4 = *(const float4*)(x + (size_t)(m0 + r) * 512 + k0 + c4);
        float4 b4 = *(const float4*)(Wxz + (size_t)(n0 + r) * 512 + k0 + c4);
        As[c4 + 0][r] = a4.x; As[c4 + 1][r] = a4.y; As[c4 + 2][r] = a4.z; As[c4 + 3][r] = a4.w;
        Bs[c4 + 0][r] = b4.x; Bs[c4 + 1][r] = b4.y; Bs[c4 + 2][r] = b4.z; Bs[c4 + 3][r] = b4.w;
        __syncthreads();
        #pragma unroll
        for (int k = 0; k < 16; ++k) {
            float a0 = As[k][tm * 4 + 0], a1 = As[k][tm * 4 + 1];
            float a2 = As[k][tm * 4 + 2], a3 = As[k][tm * 4 + 3];
            float b0 = Bs[k][tn * 4 + 0], b1 = Bs[k][tn * 4 + 1];
            float b2 = Bs[k][tn * 4 + 2], b3 = Bs[k][tn * 4 + 3];
            c[0][0] += a0 * b0; c[0][1] += a0 * b1; c[0][2] += a0 * b2; c[0][3] += a0 * b3;
            c[1][0] += a1 * b0; c[1][1] += a1 * b1; c[1][2] += a1 * b2; c[1][3] += a1 * b3;
            c[2][0] += a2 * b0; c[2][1] += a2 * b1; c[2][2] += a2 * b2; c[2][3] += a2 * b3;
            c[3][0] += a3 * b0; c[3][1] += a3 * b1; c[3][2] += a3 * b2; c[3][3] += a3 * b3;
        }
        __syncthreads();
    }
    #pragma unroll
    for (int i = 0; i < 4; ++i) {
        const int m = m0 + tm * 4 + i;
        #pragma unroll
        for (int j = 0; j < 4; ++j) {
            const int e = n0 + tn * 4 + j;
            if (e < 512) xp[(size_t)m * 512 + e] = c[i][j];
            else         z[(size_t)m * 512 + (e - 512)] = c[i][j];
        }
    }
}

// ---------------- recurrence: 64 blocks = 8 batches x 8 d-slices ----------------
__global__ __launch_bounds__(512, 2) void rec_kernel(
    const float* __restrict__ tape0, const float* __restrict__ hwork0,
    const float* __restrict__ W_h, const float* __restrict__ b_h,
    const float* __restrict__ W_write,
    const float* __restrict__ g_z, const float* __restrict__ g_r,
    const float* __restrict__ g_h, const float* __restrict__ b_gate,
    const float* __restrict__ Zbuf,
    float* __restrict__ out, float* __restrict__ tape_out,
    float* g_hn, float* g_pws, float* g_ps0, float* g_phwv,
    unsigned* flags) {
    const int b = blockIdx.x & 7;   // batch; %8 so all 8 blocks of a batch share an XCD (perf heuristic)
    const int s = blockIdx.x >> 3;  // d-slice
    const int tid = threadIdx.x;
    const int row = tid >> 3;       // 0..63   (output row within slice)
    const int l = tid & 7;          // 0..7    (k-subslice lane)
    const int d0 = s * DSL;
    const int drow = d0 + row;
    const float scale = 0.044194173824159216f;  // 1/sqrt(512)

    __shared__ __attribute__((aligned(16))) float tape[NT][PITCH];
    __shared__ __attribute__((aligned(16))) float hw2[8][PITCH];   // h_work, e = l*64+j at hw2[l][j]
    __shared__ __attribute__((aligned(16))) float red[8][PITCH];
    __shared__ __attribute__((aligned(16))) float hn_s[DSL];
    __shared__ __attribute__((aligned(16))) float wv_s[DSL];
    __shared__ __attribute__((aligned(16))) float a_l[NT];
    __shared__ __attribute__((aligned(16))) float r_l[NT];
    __shared__ __attribute__((aligned(16))) float rv[DSL];
    __shared__ __attribute__((aligned(16))) float xp_s[DSL];
    __shared__ __attribute__((aligned(16))) float z_s[DSL];

    unsigned* flagA = flags + b * 128;        // 512B apart per batch
    unsigned* flagB = flags + b * 128 + 64;

    // --- resident weights: W_h[drow][l*64 .. +64], W_write likewise (128 VGPRs) ---
    float4 wh[16], ww[16];
    {
        const float4* w1 = (const float4*)(W_h + (size_t)drow * DD + l * 64);
        const float4* w2 = (const float4*)(W_write + (size_t)drow * DD + l * 64);
        #pragma unroll
        for (int j = 0; j < 16; ++j) wh[j] = w1[j];
        #pragma unroll
        for (int j = 0; j < 16; ++j) ww[j] = w2[j];
    }
    const float bh_r = b_h[drow];
    const int de = (tid >= 64 && tid < 128) ? (tid - 64) : 0;
    const float gzr = g_z[d0 + de], grr = g_r[d0 + de], ghr = g_h[d0 + de], bgr = b_gate[d0 + de];

    // --- init: tape slice + h_work into LDS ---
    {
        const float4* tsrc = (const float4*)(tape0 + ((size_t)(b * NT + row)) * DD + d0 + l * 8);
        float4 t0 = tsrc[0], t1 = tsrc[1];
        *(float4*)&tape[row][l * 8] = t0;
        *(float4*)&tape[row][l * 8 + 4] = t1;
    }
    if (tid < 128) {
        float4 h4 = *(const float4*)(hwork0 + (size_t)b * DD + tid * 4);
        const int e = tid * 4;
        *(float4*)&hw2[e >> 6][e & 63] = h4;
    }
    __syncthreads();

    // --- initial read-score partials ---
    {
        float acc = 0.f;
        #pragma unroll
        for (int i = 0; i < 8; ++i) {
            const int dl = l * 8 + i;
            const int e = d0 + dl;
            acc += hw2[e >> 6][e & 63] * tape[row][dl];
        }
        acc = redux8(acc);
        if (l == 0) astore(&g_ps0[(b * NSL + s) * NT + row], acc);
    }
    __syncthreads();
    if (tid == 0) {
        __builtin_amdgcn_s_waitcnt(0);
        __hip_atomic_fetch_add(flagB, 1u, __ATOMIC_RELAXED, __HIP_MEMORY_SCOPE_AGENT);
        while (__hip_atomic_load(flagB, __ATOMIC_RELAXED, __HIP_MEMORY_SCOPE_AGENT) < 8u) {}
    }
    __syncthreads();
    if (tid < 64) {
        float s0 = 0.f;
        #pragma unroll
        for (int ss = 0; ss < 8; ++ss) s0 += aload(&g_ps0[(b * NSL + ss) * NT + tid]);
        r_l[tid] = softmax64(s0 * scale);
    }
    __syncthreads();
    {   // initial read_val from tape_init
        const int nc = tid >> 6, d = tid & 63;
        float acc = 0.f;
        #pragma unroll
        for (int i = 0; i < 8; ++i) acc += r_l[nc * 8 + i] * tape[nc * 8 + i][d];
        red[nc][d] = acc;
    }
    __syncthreads();
    if (tid < 64) {
        float acc = 0.f;
        #pragma unroll
        for (int nc = 0; nc < 8; ++nc) acc += red[nc][tid];
        rv[tid] = acc;
    }
    if (tid >= 64 && tid < 128) {          // prefetch xp(t=0): xp lives in out region
        xp_s[tid - 64] = out[((size_t)(b * TT)) * DD + d0 + (tid - 64)];
    } else if (tid >= 128 && tid < 192) {  // prefetch z(t=0)
        z_s[tid - 128] = Zbuf[((size_t)(b * TT)) * DD + d0 + (tid - 128)];
    }
    __syncthreads();

    // ---------------- main scan ----------------
    for (int t = 0; t < TT; ++t) {
        // A: h_new(slice) = tanh(xp + W_h . h_work + read_val + b_h)
        {
            float acc = dot64(wh, &hw2[l][0]);
            acc = redux8(acc);
            float hn = tanhf(acc + xp_s[row] + rv[row] + bh_r);
            if (l == 0) hn_s[row] = hn;
        }
        __syncthreads();
        // B: publish h_new slice; epilogue out(t)
        if (tid < 64) {
            astore(&g_hn[b * DD + d0 + tid], hn_s[tid]);
        } else if (tid < 128) {
            const int d = tid - 64;
            const float h = hn_s[d];
            float g = z_s[d] * gzr + rv[d] * grr + h * ghr + bgr;
            g = fminf(fmaxf(g, -20.f), 20.f);
            const float sig = 1.f / (1.f + __expf(-g));
            out[((size_t)(b * TT + t)) * DD + d0 + d] = h * g * sig;
        }
        __syncthreads();   // drains vmcnt for all waves before flag bump
        // C: sync A
        if (tid == 0) {
            __builtin_amdgcn_s_waitcnt(0);
            __hip_atomic_fetch_add(flagA, 1u, __ATOMIC_RELAXED, __HIP_MEMORY_SCOPE_AGENT);
            const unsigned tgt = 8u * (unsigned)(t + 1);
            while (__hip_atomic_load(flagA, __ATOMIC_RELAXED, __HIP_MEMORY_SCOPE_AGENT) < tgt) {}
        }
        __syncthreads();
        // D: gather full h_new -> hw2 (next h_work)
        if (tid < 128) {
            const int e = tid * 4;
            float v0 = aload(&g_hn[b * DD + e + 0]);
            float v1 = aload(&g_hn[b * DD + e + 1]);
            float v2 = aload(&g_hn[b * DD + e + 2]);
            float v3 = aload(&g_hn[b * DD + e + 3]);
            float4 h4; h4.x = v0; h4.y = v1; h4.z = v2; h4.w = v3;
            *(float4*)&hw2[e >> 6][e & 63] = h4;
        }
        __syncthreads();
        // E: write_val(slice) = W_write . h_new
        {
            float acc = dot64(ww, &hw2[l][0]);
            acc = redux8(acc);
            if (l == 0) wv_s[row] = acc;
        }
        __syncthreads();
        // F: partial dots against OLD tape: ws(n), s0(n) = h_new.tape_old(n), hwv
        {
            float accw = 0.f, acc0 = 0.f;
            #pragma unroll
            for (int i = 0; i < 8; ++i) {
                const int dl = l * 8 + i;
                const float tp = tape[row][dl];
                accw += wv_s[dl] * tp;
                acc0 += hn_s[dl] * tp;
            }
            accw = redux8(accw);
            acc0 = redux8(acc0);
            if (l == 0) {
                astore(&g_pws[(b * NSL + s) * NT + row], accw);
                astore(&g_ps0[(b * NSL + s) * NT + row], acc0);
            }
        }
        if (tid < 8) {
            float a = 0.f;
            #pragma unroll
            for (int i = 0; i < 8; ++i) a += hn_s[tid * 8 + i] * wv_s[tid * 8 + i];
            a = redux8(a);
            if (tid == 0) astore(&g_phwv[b * NSL + s], a);
        }
        __syncthreads();
        // G: sync B (+ prefetch next xp/z on idle waves)
        if (tid == 0) {
            __builtin_amdgcn_s_waitcnt(0);
            __hip_atomic_fetch_add(flagB, 1u, __ATOMIC_RELAXED, __HIP_MEMORY_SCOPE_AGENT);
            const unsigned tgt = 8u * (unsigned)(t + 2);
            while (__hip_atomic_load(flagB, __ATOMIC_RELAXED, __HIP_MEMORY_SCOPE_AGENT) < tgt) {}
        } else if (tid >= 64 && tid < 128) {
            const int tn = (t + 1 < TT) ? (t + 1) : t;  // last-iter value unused
            xp_s[tid - 64] = out[((size_t)(b * TT + tn)) * DD + d0 + (tid - 64)];
        } else if (tid >= 128 && tid < 192) {
            const int tn = (t + 1 < TT) ? (t + 1) : t;
            z_s[tid - 128] = Zbuf[((size_t)(b * TT + tn)) * DD + d0 + (tid - 128)];
        }
        __syncthreads();
        // H: reduce partials; write softmax a(n); fused next read score; softmax r(n)
        if (tid < 64) {
            float ws = 0.f, s0 = 0.f;
            #pragma unroll
            for (int ss = 0; ss < 8; ++ss) {
                ws += aload(&g_pws[(b * NSL + ss) * NT + tid]);
                s0 += aload(&g_ps0[(b * NSL + ss) * NT + tid]);
            }
            float hwv = 0.f;
            #pragma unroll
            for (int ss = 0; ss < 8; ++ss) hwv += aload(&g_phwv[b * NSL + ss]);
            const float a = softmax64(ws * scale);
            a_l[tid] = a;
            // h_new . tape_new(n) = (1-a)*s0 + a*hwv   (read score for t+1)
            const float scn = scale * ((1.f - a) * s0 + a * hwv);
            r_l[tid] = softmax64(scn);
        }
        __syncthreads();
        // I: tape slice update
        {
            const float an = a_l[row];
            #pragma unroll
            for (int i = 0; i < 8; i += 4) {
                float4 tp = *(const float4*)&tape[row][l * 8 + i];
                float4 w4 = *(const float4*)&wv_s[l * 8 + i];
                tp.x += an * (w4.x - tp.x);
                tp.y += an * (w4.y - tp.y);
                tp.z += an * (w4.z - tp.z);
                tp.w += an * (w4.w - tp.w);
                *(float4*)&tape[row][l * 8 + i] = tp;
            }
        }
        __syncthreads();
        // J/K: read_val(slice) for t+1 from updated tape
        {
            const int nc = tid >> 6, d = tid & 63;
            float acc = 0.f;
            #pragma unroll
            for (int i = 0; i < 8; ++i) acc += r_l[nc * 8 + i] * tape[nc * 8 + i][d];
            red[nc][d] = acc;
        }
        __syncthreads();
        if (tid < 64) {
            float acc = 0.f;
            #pragma unroll
            for (int nc = 0; nc < 8; ++nc) acc += red[nc][tid];
            rv[tid] = acc;
        }
        __syncthreads();
    }

    // final tape slice -> output
    {
        float4 t0 = *(const float4*)&tape[row][l * 8];
        float4 t1 = *(const float4*)&tape[row][l * 8 + 4];
        float* dst = tape_out + ((size_t)(b * NT + row)) * DD + d0 + l * 8;
        *(float4*)dst = t0;
        *(float4*)(dst + 4) = t1;
    }
}

extern "C" void kernel_launch(void* const* d_in, const int* in_sizes, int n_in,
                              void* d_out, int out_size, void* d_ws, size_t ws_size,
                              hipStream_t stream) {
    const float* x       = (const float*)d_in[0];   // [8,1024,512]
    const float* tape0   = (const float*)d_in[1];   // [8,64,512]
    const float* hwork0  = (const float*)d_in[2];   // [8,512]
    const float* W_h     = (const float*)d_in[3];   // [512,512]
    const float* W_xz    = (const float*)d_in[4];   // [1024,512]
    const float* b_h     = (const float*)d_in[5];   // [512]
    const float* W_write = (const float*)d_in[6];   // [512,512]
    const float* g_z     = (const float*)d_in[7];
    const float* g_r     = (const float*)d_in[8];
    const float* g_h     = (const float*)d_in[9];
    const float* b_gate  = (const float*)d_in[10];

    float* out  = (float*)d_out;                       // outs [8,1024,512]
    float* tout = out + (size_t)BB * TT * DD;          // tape_final [8,64,512]

    char* ws = (char*)d_ws;
    unsigned* flags = (unsigned*)ws;                   // 4 KB, zeroed each launch
    float* g_hn   = (float*)(ws + 4096);               // 16 KB
    float* g_pws  = (float*)(ws + 4096 + 16384);       // 16 KB
    float* g_ps0  = (float*)(ws + 4096 + 32768);       // 16 KB
    float* g_phwv = (float*)(ws + 4096 + 49152);       // 256 B
    float* Zbuf   = (float*)(ws + 65536);              // 16 MB

    (void)in_sizes; (void)n_in; (void)out_size; (void)ws_size;

    hipMemsetAsync(flags, 0, 4096, stream);
    // projection: x_proj -> out region (read then overwritten in-place by scan), z -> ws
    dim3 pgrid(128, 16);
    proj_kernel<<<pgrid, 256, 0, stream>>>(x, W_xz, out, Zbuf);
    rec_kernel<<<64, 512, 0, stream>>>(tape0, hwork0, W_h, b_h, W_write,
                                       g_z, g_r, g_h, b_gate, Zbuf,
                                       out, tout, g_hn, g_pws, g_ps0, g_phwv, flags);
}

// Round 2
// 5484.018 us; speedup vs baseline: 1.0847x; 1.0847x over previous
//
#include <hip/hip_runtime.h>
#include <math.h>

#define BB 8
#define TT 1024
#define DD 512
#define NT 64       // tape rows
#define NSL 8       // slices (blocks per batch)
#define DSL 64      // slice width in d
#define PITCH 68    // LDS pitch for tape rows

typedef unsigned long long u64;

// ---------------- tagged cross-block atomics (agent scope, relaxed) ----------------
static __device__ __forceinline__ u64 aload64(const u64* p) {
    return __hip_atomic_load(p, __ATOMIC_RELAXED, __HIP_MEMORY_SCOPE_AGENT);
}
static __device__ __forceinline__ void astore64(u64* p, u64 v) {
    __hip_atomic_store(p, v, __ATOMIC_RELAXED, __HIP_MEMORY_SCOPE_AGENT);
}
static __device__ __forceinline__ u64 packf(float v, unsigned tag) {
    union { float f; unsigned u; } c; c.f = v;
    return ((u64)tag << 32) | (u64)c.u;
}
static __device__ __forceinline__ float unpackf(u64 w) {
    union { unsigned u; float f; } c; c.u = (unsigned)w;
    return c.f;
}

static __device__ __forceinline__ float redux8(float v) {
    v += __shfl_xor(v, 1);
    v += __shfl_xor(v, 2);
    v += __shfl_xor(v, 4);
    return v;
}

// softmax across 64 lanes (wave0 only; lane i holds score i)
static __device__ __forceinline__ float softmax64(float sc) {
    float m = sc;
    #pragma unroll
    for (int off = 32; off > 0; off >>= 1) m = fmaxf(m, __shfl_xor(m, off));
    float e = __expf(sc - m);
    float s = e;
    #pragma unroll
    for (int off = 32; off > 0; off >>= 1) s += __shfl_xor(s, off);
    return e / s;
}

// dot of 64 resident weights with 64 LDS floats
static __device__ __forceinline__ float dot64(const float4 (&w)[16], const float* hr) {
    float a0 = 0.f, a1 = 0.f, a2 = 0.f, a3 = 0.f;
    #pragma unroll
    for (int j = 0; j < 16; j += 4) {
        float4 h0 = *(const float4*)(hr + 4 * (j + 0));
        float4 h1 = *(const float4*)(hr + 4 * (j + 1));
        float4 h2 = *(const float4*)(hr + 4 * (j + 2));
        float4 h3 = *(const float4*)(hr + 4 * (j + 3));
        a0 += w[j + 0].x * h0.x + w[j + 0].y * h0.y + w[j + 0].z * h0.z + w[j + 0].w * h0.w;
        a1 += w[j + 1].x * h1.x + w[j + 1].y * h1.y + w[j + 1].z * h1.z + w[j + 1].w * h1.w;
        a2 += w[j + 2].x * h2.x + w[j + 2].y * h2.y + w[j + 2].z * h2.z + w[j + 2].w * h2.w;
        a3 += w[j + 3].x * h3.x + w[j + 3].y * h3.y + w[j + 3].z * h3.z + w[j + 3].w * h3.w;
    }
    return (a0 + a1) + (a2 + a3);
}

// ---------------- projection GEMM (unchanged from R1) ----------------
__global__ __launch_bounds__(256) void proj_kernel(const float* __restrict__ x,
                                                   const float* __restrict__ Wxz,
                                                   float* __restrict__ xp,
                                                   float* __restrict__ z) {
    __shared__ float As[16][66];
    __shared__ float Bs[16][66];
    const int m0 = blockIdx.x * 64;
    const int n0 = blockIdx.y * 64;
    const int tid = threadIdx.x;
    const int tm = tid / 16, tn = tid % 16;
    float c[4][4] = {};
    for (int k0 = 0; k0 < 512; k0 += 16) {
        const int r = tid >> 2, c4 = (tid & 3) * 4;
        float4 a4 = *(const float4*)(x + (size_t)(m0 + r) * 512 + k0 + c4);
        float4 b4 = *(const float4*)(Wxz + (size_t)(n0 + r) * 512 + k0 + c4);
        As[c4 + 0][r] = a4.x; As[c4 + 1][r] = a4.y; As[c4 + 2][r] = a4.z; As[c4 + 3][r] = a4.w;
        Bs[c4 + 0][r] = b4.x; Bs[c4 + 1][r] = b4.y; Bs[c4 + 2][r] = b4.z; Bs[c4 + 3][r] = b4.w;
        __syncthreads();
        #pragma unroll
        for (int k = 0; k < 16; ++k) {
            float a0 = As[k][tm * 4 + 0], a1 = As[k][tm * 4 + 1];
            float a2 = As[k][tm * 4 + 2], a3 = As[k][tm * 4 + 3];
            float b0 = Bs[k][tn * 4 + 0], b1 = Bs[k][tn * 4 + 1];
            float b2 = Bs[k][tn * 4 + 2], b3 = Bs[k][tn * 4 + 3];
            c[0][0] += a0 * b0; c[0][1] += a0 * b1; c[0][2] += a0 * b2; c[0][3] += a0 * b3;
            c[1][0] += a1 * b0; c[1][1] += a1 * b1; c[1][2] += a1 * b2; c[1][3] += a1 * b3;
            c[2][0] += a2 * b0; c[2][1] += a2 * b1; c[2][2] += a2 * b2; c[2][3] += a2 * b3;
            c[3][0] += a3 * b0; c[3][1] += a3 * b1; c[3][2] += a3 * b2; c[3][3] += a3 * b3;
        }
        __syncthreads();
    }
    #pragma unroll
    for (int i = 0; i < 4; ++i) {
        const int m = m0 + tm * 4 + i;
        #pragma unroll
        for (int j = 0; j < 4; ++j) {
            const int e = n0 + tn * 4 + j;
            if (e < 512) xp[(size_t)m * 512 + e] = c[i][j];
            else         z[(size_t)m * 512 + (e - 512)] = c[i][j];
        }
    }
}

// ---------------- recurrence: 64 blocks = 8 batches x 8 d-slices ----------------
// Sync protocol: every cross-block word is u64 (tag<<32 | float). Producers
// fire tagged stores (no drain, no flags); consumers poll the words directly
// (~1 L3 round trip per sync instead of ~4). Double-buffered by step parity;
// the dependency chain guarantees no 2-ahead overwrite before consumption.
__global__ __launch_bounds__(512, 2) void rec_kernel(
    const float* __restrict__ tape0, const float* __restrict__ hwork0,
    const float* __restrict__ W_h, const float* __restrict__ b_h,
    const float* __restrict__ W_write,
    const float* __restrict__ g_z, const float* __restrict__ g_r,
    const float* __restrict__ g_h, const float* __restrict__ b_gate,
    const float* __restrict__ Zbuf,
    float* __restrict__ out, float* __restrict__ tape_out,
    u64* g_hn, u64* g_pws, u64* g_ps0, u64* g_phwv) {
    const int b = blockIdx.x & 7;   // batch (blocks of a batch hit one XCD under %8 round-robin)
    const int s = blockIdx.x >> 3;  // d-slice
    const int tid = threadIdx.x;
    const int row = tid >> 3;       // 0..63
    const int l = tid & 7;          // 0..7
    const int d0 = s * DSL;
    const int drow = d0 + row;
    const float scale = 0.044194173824159216f;  // 1/sqrt(512)

    __shared__ __attribute__((aligned(16))) float tape[NT][PITCH];
    __shared__ __attribute__((aligned(16))) float hw2[8][PITCH];
    __shared__ __attribute__((aligned(16))) float red[8][PITCH];
    __shared__ __attribute__((aligned(16))) float hn_s[DSL];
    __shared__ __attribute__((aligned(16))) float wv_s[DSL];
    __shared__ __attribute__((aligned(16))) float a_l[NT];
    __shared__ __attribute__((aligned(16))) float r_l[NT];   // holds c1 = r*(1-a)
    __shared__ __attribute__((aligned(16))) float rv[DSL];
    __shared__ __attribute__((aligned(16))) float xp_s[DSL];
    __shared__ __attribute__((aligned(16))) float z_s[DSL];
    __shared__ float c2_s;                                    // sum_n r(n)*a(n)

    // --- resident weights ---
    float4 wh[16], ww[16];
    {
        const float4* w1 = (const float4*)(W_h + (size_t)drow * DD + l * 64);
        const float4* w2 = (const float4*)(W_write + (size_t)drow * DD + l * 64);
        #pragma unroll
        for (int j = 0; j < 16; ++j) wh[j] = w1[j];
        #pragma unroll
        for (int j = 0; j < 16; ++j) ww[j] = w2[j];
    }
    const float bh_r = b_h[drow];
    const int de = (tid >= 64 && tid < 128) ? (tid - 64) : 0;
    const float gzr = g_z[d0 + de], grr = g_r[d0 + de], ghr = g_h[d0 + de], bgr = b_gate[d0 + de];

    // --- init LDS: tape slice + h_work ---
    {
        const float4* tsrc = (const float4*)(tape0 + ((size_t)(b * NT + row)) * DD + d0 + l * 8);
        float4 t0 = tsrc[0], t1 = tsrc[1];
        *(float4*)&tape[row][l * 8] = t0;
        *(float4*)&tape[row][l * 8 + 4] = t1;
    }
    if (tid < 128) {
        float4 h4 = *(const float4*)(hwork0 + (size_t)b * DD + tid * 4);
        const int e = tid * 4;
        *(float4*)&hw2[e >> 6][e & 63] = h4;
    }
    if (tid == 0) c2_s = 0.f;
    __syncthreads();

    // --- init event e=0 (buf 0, tag 1): read-score partials from h_work ---
    {
        float acc = 0.f;
        #pragma unroll
        for (int i = 0; i < 8; ++i) {
            const int dl = l * 8 + i;
            const int e = d0 + dl;
            acc += hw2[e >> 6][e & 63] * tape[row][dl];
        }
        acc = redux8(acc);
        if (l == 0) {
            astore64(&g_ps0[((0 * 8 + b) * 8 + s) * 64 + row], packf(acc, 1u));
            wv_s[row] = 0.f;   // so c2_s*wv_s term is well-defined at init
        }
    }
    // poll init partials (wave0) + prefetch xp/z(t=0) (waves 1,2)
    if (tid < 64) {
        u64 w8[8];
        const u64* ps = &g_ps0[((0 * 8 + b) * 8 + 0) * 64 + tid];
        bool ok;
        do {
            ok = true;
            #pragma unroll
            for (int ss = 0; ss < 8; ++ss) w8[ss] = aload64(ps + ss * 64);
            #pragma unroll
            for (int ss = 0; ss < 8; ++ss) ok = ok && ((unsigned)(w8[ss] >> 32) == 1u);
        } while (!ok);
        float s0 = 0.f;
        #pragma unroll
        for (int ss = 0; ss < 8; ++ss) s0 += unpackf(w8[ss]);
        float r = softmax64(s0 * scale);
        r_l[tid] = r;          // c1 with a=0
        a_l[tid] = 0.f;
    } else if (tid < 128) {
        xp_s[tid - 64] = out[((size_t)(b * TT)) * DD + d0 + (tid - 64)];
    } else if (tid < 192) {
        z_s[tid - 128] = Zbuf[((size_t)(b * TT)) * DD + d0 + (tid - 128)];
    }
    __syncthreads();
    {   // init rv partials
        const int nc = tid >> 6, d = tid & 63;
        float acc = 0.f;
        #pragma unroll
        for (int i = 0; i < 8; ++i) acc += r_l[nc * 8 + i] * tape[nc * 8 + i][d];
        red[nc][d] = acc;
    }
    __syncthreads();
    if (tid < 64) {
        float acc = c2_s * wv_s[tid];   // = 0 at init
        #pragma unroll
        for (int nc = 0; nc < 8; ++nc) acc += red[nc][tid];
        rv[tid] = acc;
    }
    __syncthreads();

    // ---------------- main scan: 6 barriers, 2 single-RT polls per step ----------------
    for (int t = 0; t < TT; ++t) {
        // P1: h_new(slice)
        {
            float acc = dot64(wh, &hw2[l][0]);
            acc = redux8(acc);
            float hn = tanhf(acc + xp_s[row] + rv[row] + bh_r);
            if (l == 0) hn_s[row] = hn;
        }
        __syncthreads();
        // P2: publish h_new (tagged) + epilogue; then poll-gather full h_new
        {
            const unsigned htag = (unsigned)(t + 1);
            const int hbuf = t & 1;
            u64* hb = &g_hn[((size_t)hbuf * 8 + b) * 512];
            if (tid < 64) {
                astore64(hb + d0 + tid, packf(hn_s[tid], htag));
            } else if (tid < 128) {
                const int d = tid - 64;
                const float h = hn_s[d];
                float g = z_s[d] * gzr + rv[d] * grr + h * ghr + bgr;
                g = fminf(fmaxf(g, -20.f), 20.f);
                const float sig = 1.f / (1.f + __expf(-g));
                out[((size_t)(b * TT + t)) * DD + d0 + d] = h * g * sig;
            }
            if (tid < 128) {
                u64* base = hb + tid * 4;
                u64 a0, a1, a2, a3;
                bool ok;
                do {
                    a0 = aload64(base + 0); a1 = aload64(base + 1);
                    a2 = aload64(base + 2); a3 = aload64(base + 3);
                    ok = ((unsigned)(a0 >> 32) == htag) && ((unsigned)(a1 >> 32) == htag) &&
                         ((unsigned)(a2 >> 32) == htag) && ((unsigned)(a3 >> 32) == htag);
                } while (!ok);
                const int e = tid * 4;
                float4 h4;
                h4.x = unpackf(a0); h4.y = unpackf(a1); h4.z = unpackf(a2); h4.w = unpackf(a3);
                *(float4*)&hw2[e >> 6][e & 63] = h4;
            }
        }
        __syncthreads();
        // P3: write_val(slice) = W_write . h_new
        {
            float acc = dot64(ww, &hw2[l][0]);
            acc = redux8(acc);
            if (l == 0) wv_s[row] = acc;
        }
        __syncthreads();
        // P4: score partials vs OLD tape + publish; wave0 polls+softmaxes; waves1/2 prefetch
        {
            const unsigned etag = (unsigned)(t + 2);
            const int ebuf = (t + 1) & 1;
            float accw = 0.f, acc0 = 0.f;
            #pragma unroll
            for (int i = 0; i < 8; ++i) {
                const int dl = l * 8 + i;
                const float tp = tape[row][dl];
                accw += wv_s[dl] * tp;
                acc0 += hn_s[dl] * tp;
            }
            accw = redux8(accw);
            acc0 = redux8(acc0);
            if (l == 0) {
                astore64(&g_pws[((ebuf * 8 + b) * 8 + s) * 64 + row], packf(accw, etag));
                astore64(&g_ps0[((ebuf * 8 + b) * 8 + s) * 64 + row], packf(acc0, etag));
            }
            if (tid < 8) {
                float a2 = 0.f;
                #pragma unroll
                for (int i = 0; i < 8; ++i) a2 += hn_s[tid * 8 + i] * wv_s[tid * 8 + i];
                a2 = redux8(a2);
                if (tid == 0) astore64(&g_phwv[(ebuf * 8 + b) * 8 + s], packf(a2, etag));
            }
            if (tid < 64) {
                const int n = tid;
                const u64* pw = &g_pws[((ebuf * 8 + b) * 8 + 0) * 64 + n];
                const u64* ps = &g_ps0[((ebuf * 8 + b) * 8 + 0) * 64 + n];
                const u64* pv = &g_phwv[(ebuf * 8 + b) * 8];
                u64 w8[8], s8[8], v8[8];
                bool ok;
                do {
                    ok = true;
                    #pragma unroll
                    for (int ss = 0; ss < 8; ++ss) w8[ss] = aload64(pw + ss * 64);
                    #pragma unroll
                    for (int ss = 0; ss < 8; ++ss) s8[ss] = aload64(ps + ss * 64);
                    #pragma unroll
                    for (int ss = 0; ss < 8; ++ss) v8[ss] = aload64(pv + ss);
                    #pragma unroll
                    for (int ss = 0; ss < 8; ++ss)
                        ok = ok && ((unsigned)(w8[ss] >> 32) == etag) &&
                                   ((unsigned)(s8[ss] >> 32) == etag) &&
                                   ((unsigned)(v8[ss] >> 32) == etag);
                } while (!ok);
                float ws = 0.f, s0 = 0.f, hwv = 0.f;
                #pragma unroll
                for (int ss = 0; ss < 8; ++ss) {
                    ws += unpackf(w8[ss]); s0 += unpackf(s8[ss]); hwv += unpackf(v8[ss]);
                }
                const float a = softmax64(ws * scale);
                a_l[n] = a;
                const float scn = scale * ((1.f - a) * s0 + a * hwv);
                const float r = softmax64(scn);
                r_l[n] = r * (1.f - a);   // c1
                float ra = r * a;
                #pragma unroll
                for (int off = 32; off > 0; off >>= 1) ra += __shfl_xor(ra, off);
                if (tid == 0) c2_s = ra;
            } else if (tid < 128) {
                const int tn = (t + 1 < TT) ? (t + 1) : t;
                xp_s[tid - 64] = out[((size_t)(b * TT + tn)) * DD + d0 + (tid - 64)];
            } else if (tid < 192) {
                const int tn = (t + 1 < TT) ? (t + 1) : t;
                z_s[tid - 128] = Zbuf[((size_t)(b * TT + tn)) * DD + d0 + (tid - 128)];
            }
        }
        __syncthreads();
        // P5: rv partials over OLD tape with c1 weights
        {
            const int nc = tid >> 6, d = tid & 63;
            float acc = 0.f;
            #pragma unroll
            for (int i = 0; i < 8; ++i) acc += r_l[nc * 8 + i] * tape[nc * 8 + i][d];
            red[nc][d] = acc;
        }
        __syncthreads();
        // P6: rv finish (wave0-width) + tape update (all threads), concurrent
        if (tid < 64) {
            float acc = c2_s * wv_s[tid];
            #pragma unroll
            for (int nc = 0; nc < 8; ++nc) acc += red[nc][tid];
            rv[tid] = acc;
        }
        {
            const float an = a_l[row];
            #pragma unroll
            for (int i = 0; i < 8; i += 4) {
                float4 tp = *(const float4*)&tape[row][l * 8 + i];
                float4 w4 = *(const float4*)&wv_s[l * 8 + i];
                tp.x += an * (w4.x - tp.x);
                tp.y += an * (w4.y - tp.y);
                tp.z += an * (w4.z - tp.z);
                tp.w += an * (w4.w - tp.w);
                *(float4*)&tape[row][l * 8 + i] = tp;
            }
        }
        __syncthreads();
    }

    // final tape slice -> output
    {
        float4 t0 = *(const float4*)&tape[row][l * 8];
        float4 t1 = *(const float4*)&tape[row][l * 8 + 4];
        float* dst = tape_out + ((size_t)(b * NT + row)) * DD + d0 + l * 8;
        *(float4*)dst = t0;
        *(float4*)(dst + 4) = t1;
    }
}

extern "C" void kernel_launch(void* const* d_in, const int* in_sizes, int n_in,
                              void* d_out, int out_size, void* d_ws, size_t ws_size,
                              hipStream_t stream) {
    const float* x       = (const float*)d_in[0];   // [8,1024,512]
    const float* tape0   = (const float*)d_in[1];   // [8,64,512]
    const float* hwork0  = (const float*)d_in[2];   // [8,512]
    const float* W_h     = (const float*)d_in[3];   // [512,512]
    const float* W_xz    = (const float*)d_in[4];   // [1024,512]
    const float* b_h     = (const float*)d_in[5];   // [512]
    const float* W_write = (const float*)d_in[6];   // [512,512]
    const float* g_z     = (const float*)d_in[7];
    const float* g_r     = (const float*)d_in[8];
    const float* g_h     = (const float*)d_in[9];
    const float* b_gate  = (const float*)d_in[10];

    float* out  = (float*)d_out;                       // outs [8,1024,512]
    float* tout = out + (size_t)BB * TT * DD;          // tape_final [8,64,512]

    char* ws = (char*)d_ws;
    u64* g_hn   = (u64*)ws;                            // [2][8][512]  = 64 KB
    u64* g_pws  = (u64*)(ws + 65536);                  // [2][8][8][64] = 64 KB
    u64* g_ps0  = (u64*)(ws + 131072);                 // [2][8][8][64] = 64 KB
    u64* g_phwv = (u64*)(ws + 196608);                 // [2][8][8]    = 1 KB
    float* Zbuf = (float*)(ws + 262144);               // 16 MB

    (void)in_sizes; (void)n_in; (void)out_size; (void)ws_size;

    // projection: x_proj -> out region (read then overwritten in-place by scan), z -> ws
    dim3 pgrid(128, 16);
    proj_kernel<<<pgrid, 256, 0, stream>>>(x, W_xz, out, Zbuf);
    rec_kernel<<<64, 512, 0, stream>>>(tape0, hwork0, W_h, b_h, W_write,
                                       g_z, g_r, g_h, b_gate, Zbuf,
                                       out, tout, g_hn, g_pws, g_ps0, g_phwv);
}